// Round 3
// baseline (342.526 us; speedup 1.0000x reference)
//
#include <hip/hip_runtime.h>

// Problem constants
#define B_ 2
#define N_ 196608
#define K_ 9
#define F_ 64

typedef __attribute__((ext_vector_type(8))) short short8;
typedef __attribute__((ext_vector_type(8))) unsigned short ushort8;
typedef __attribute__((ext_vector_type(4))) float f32x4;

__device__ __forceinline__ unsigned short f2bf(float f) {
  unsigned u = __builtin_bit_cast(unsigned, f);
  u = (u + 0x7fffu + ((u >> 16) & 1u)) >> 16;   // RNE
  return (unsigned short)u;
}

// x fp32 [B][N][64] -> xb bf16 [N][B][64] (batch-interleaved rows, 256 B per n)
// thread i: n = i>>3, b = (i>>2)&1, q4 = i&3 -> 16 floats
__global__ __launch_bounds__(256) void cvt_x_kernel(const float* __restrict__ x,
                                                    unsigned short* __restrict__ xb) {
  const long i = (long)blockIdx.x * 256 + threadIdx.x;
  const long n = i >> 3;
  const int b = (int)((i >> 2) & 1);
  const int q4 = (int)(i & 3);
  const float4* src = (const float4*)(x + ((size_t)b * N_ + n) * F_ + q4 * 16);
  float4 v[4];
#pragma unroll
  for (int j = 0; j < 4; ++j) v[j] = src[j];
  ushort8 r0, r1;
  r0[0] = f2bf(v[0].x); r0[1] = f2bf(v[0].y); r0[2] = f2bf(v[0].z); r0[3] = f2bf(v[0].w);
  r0[4] = f2bf(v[1].x); r0[5] = f2bf(v[1].y); r0[6] = f2bf(v[1].z); r0[7] = f2bf(v[1].w);
  r1[0] = f2bf(v[2].x); r1[1] = f2bf(v[2].y); r1[2] = f2bf(v[2].z); r1[3] = f2bf(v[2].w);
  r1[4] = f2bf(v[3].x); r1[5] = f2bf(v[3].y); r1[6] = f2bf(v[3].z); r1[7] = f2bf(v[3].w);
  ushort8* dst = (ushort8*)(xb + ((size_t)n * 2 + b) * F_ + q4 * 16);
  dst[0] = r0;
  dst[1] = r1;
}

// W fp32 [9][64][64] (k,f,o) -> Wt bf16 [9][64][64] (k,o,f)
__global__ __launch_bounds__(256) void cvt_w_kernel(const float* __restrict__ W,
                                                    unsigned short* __restrict__ wt) {
  const int i = blockIdx.x * 256 + threadIdx.x;
  const int k = i >> 12;
  const int rem = i & 4095;
  const int o = rem >> 6;
  const int f = rem & 63;
  wt[i] = f2bf(W[(k << 12) + (f << 6) + o]);
}

// Main: block = 256 thr (4 waves); tile = 64 rows, BOTH batches, 64 cols.
// Wave w: rows w*16 .. w*16+15 (one 16-row subtile), both b-planes, 4 col-tiles.
// All 36 A-fragment gathers pinned upfront via sched_barrier (MLP).
__global__ __launch_bounds__(256, 2) void nhconv_main(
    const short* __restrict__ xb,    // [N][2][64] bf16 bits
    const int* __restrict__ adjc,    // [N][9] int32
    const short* __restrict__ wt,    // [9][64][64] bf16 bits, Wt[k][o][f]
    const float* __restrict__ bias,  // [64]
    float* __restrict__ out) {       // [2][N][64] fp32
  __shared__ int s_adj[64 * K_];

  const int n0 = blockIdx.x * 64;
  const int tid = (int)threadIdx.x;

  // Cooperative coalesced load of this tile's adjacency (576 ints)
  for (int i = tid; i < 64 * K_; i += 256) s_adj[i] = adjc[n0 * K_ + i];
  __syncthreads();

  const int w = tid >> 6;          // wave 0..3
  const int l = tid & 63;          // lane
  const int q = l >> 4;            // quad 0..3
  const int c = l & 15;

  const int r = w * 16 + c;        // local row this lane's A-fragments cover
  const int foq = q * 8;           // lane's k-chunk offset (shorts)

  // ---- Issue ALL 36 gather loads upfront, then pin with sched_barrier ----
  short8 A0[K_][2], A1[K_][2];     // [k][fs] for plane 0 / plane 1
#pragma unroll
  for (int k = 0; k < K_; ++k) {
    const short* p = xb + ((size_t)s_adj[r * K_ + k] << 7) + foq;  // row base (256B/n)
    A0[k][0] = *(const short8*)p;
    A0[k][1] = *(const short8*)(p + 32);
    A1[k][0] = *(const short8*)(p + 64);
    A1[k][1] = *(const short8*)(p + 96);
  }
  __builtin_amdgcn_sched_barrier(0);  // nothing crosses: loads stay hoisted

  f32x4 acc[2][4];
#pragma unroll
  for (int p = 0; p < 2; ++p)
#pragma unroll
    for (int ct = 0; ct < 4; ++ct)
      acc[p][ct] = (f32x4){0.f, 0.f, 0.f, 0.f};

  // ---- MFMA loop: each B-frag feeds 2 MFMAs (both batches) ----
#pragma unroll
  for (int k = 0; k < K_; ++k) {
#pragma unroll
    for (int fs = 0; fs < 2; ++fs) {
      const short* wk = wt + (k << 12) + fs * 32 + foq + (c << 6);  // + ct*1024
#pragma unroll
      for (int ct = 0; ct < 4; ++ct) {
        const short8 bf = *(const short8*)(wk + (ct << 10));
        acc[0][ct] = __builtin_amdgcn_mfma_f32_16x16x32_bf16(A0[k][fs], bf, acc[0][ct], 0, 0, 0);
        acc[1][ct] = __builtin_amdgcn_mfma_f32_16x16x32_bf16(A1[k][fs], bf, acc[1][ct], 0, 0, 0);
      }
    }
  }

  // Epilogue: C col = lane&15, row = quad*4 + reg
  float bv[4];
#pragma unroll
  for (int ct = 0; ct < 4; ++ct) bv[ct] = bias[ct * 16 + c];

#pragma unroll
  for (int p = 0; p < 2; ++p) {
    const size_t outbase = ((size_t)p * N_ + (size_t)(n0 + w * 16)) * F_;
#pragma unroll
    for (int ct = 0; ct < 4; ++ct) {
#pragma unroll
      for (int rr = 0; rr < 4; ++rr) {
        const int row = q * 4 + rr;
        out[outbase + (size_t)row * F_ + ct * 16 + c] = acc[p][ct][rr] + bv[ct];
      }
    }
  }
}

extern "C" void kernel_launch(void* const* d_in, const int* in_sizes, int n_in,
                              void* d_out, int out_size, void* d_ws, size_t ws_size,
                              hipStream_t stream) {
  const float* x = (const float*)d_in[0];
  const int* adjc = (const int*)d_in[1];
  const float* W = (const float*)d_in[2];
  const float* bias = (const float*)d_in[3];
  float* out = (float*)d_out;

  unsigned short* xb = (unsigned short*)d_ws;                    // 50,331,648 B
  unsigned short* wt = (unsigned short*)((char*)d_ws + (size_t)B_ * N_ * F_ * 2);

  // x convert+interleave: 25,165,824 elems / 16 per thread / 256 = 6144 blocks
  cvt_x_kernel<<<6144, 256, 0, stream>>>(x, xb);
  // W convert+transpose: 36864 elems / 256 = 144 blocks
  cvt_w_kernel<<<144, 256, 0, stream>>>(W, wt);

  // 64 rows per block, both batches: N/64 = 3072 blocks
  nhconv_main<<<3072, 256, 0, stream>>>((const short*)xb, adjc, (const short*)wt,
                                        bias, out);
}

// Round 4
// 305.617 us; speedup vs baseline: 1.1208x; 1.1208x over previous
//
#include <hip/hip_runtime.h>

// Problem constants
#define B_ 2
#define N_ 196608
#define K_ 9
#define F_ 64
#define ROWS 64   // n-rows per block
#define ROWB 256  // bytes per xb row (both batch planes: [n][2][64] bf16)

typedef __attribute__((ext_vector_type(8))) short short8;
typedef __attribute__((ext_vector_type(8))) unsigned short ushort8;
typedef __attribute__((ext_vector_type(4))) float f32x4;

__device__ __forceinline__ unsigned short f2bf(float f) {
  unsigned u = __builtin_bit_cast(unsigned, f);
  u = (u + 0x7fffu + ((u >> 16) & 1u)) >> 16;  // RNE
  return (unsigned short)u;
}

// x fp32 [B][N][64] -> xb bf16 [N][B][64] (batch-interleaved rows, 256 B per n)
__global__ __launch_bounds__(256) void cvt_x_kernel(const float* __restrict__ x,
                                                    unsigned short* __restrict__ xb) {
  const long i = (long)blockIdx.x * 256 + threadIdx.x;
  const long n = i >> 3;
  const int b = (int)((i >> 2) & 1);
  const int q4 = (int)(i & 3);
  const float4* src = (const float4*)(x + ((size_t)b * N_ + n) * F_ + q4 * 16);
  float4 v[4];
#pragma unroll
  for (int j = 0; j < 4; ++j) v[j] = src[j];
  ushort8 r0, r1;
  r0[0] = f2bf(v[0].x); r0[1] = f2bf(v[0].y); r0[2] = f2bf(v[0].z); r0[3] = f2bf(v[0].w);
  r0[4] = f2bf(v[1].x); r0[5] = f2bf(v[1].y); r0[6] = f2bf(v[1].z); r0[7] = f2bf(v[1].w);
  r1[0] = f2bf(v[2].x); r1[1] = f2bf(v[2].y); r1[2] = f2bf(v[2].z); r1[3] = f2bf(v[2].w);
  r1[4] = f2bf(v[3].x); r1[5] = f2bf(v[3].y); r1[6] = f2bf(v[3].z); r1[7] = f2bf(v[3].w);
  ushort8* dst = (ushort8*)(xb + ((size_t)n * 2 + b) * F_ + q4 * 16);
  dst[0] = r0;
  dst[1] = r1;
}

// W fp32 [9][64][64] (k,f,o) -> Wt bf16 [9][64][64] (k,o,f)
__global__ __launch_bounds__(256) void cvt_w_kernel(const float* __restrict__ W,
                                                    unsigned short* __restrict__ wt) {
  const int i = blockIdx.x * 256 + threadIdx.x;
  const int k = i >> 12;
  const int rem = i & 4095;
  const int o = rem >> 6;
  const int f = rem & 63;
  wt[i] = f2bf(W[(k << 12) + (f << 6) + o]);
}

// Main: block = 256 thr (4 waves); tile = 64 rows, both batch planes, 64 cols.
// Gather staging via global_load_lds DMA (deep vmcnt MLP, no VGPR involvement),
// double-buffered over k. Per-row XOR chunk swizzle -> conflict-free ds_read_b128.
__global__ __launch_bounds__(256, 3) void nhconv_main(
    const short* __restrict__ xb,    // [N][2][64] bf16 bits, 256 B per n
    const int* __restrict__ adjc,    // [N][9] int32
    const short* __restrict__ wt,    // [9][64][64] bf16 bits, Wt[k][o][f]
    const float* __restrict__ bias,  // [64]
    float* __restrict__ out) {       // [2][N][64] fp32
  __shared__ short abuf[2][ROWS * 128];  // 2 x 16 KB gathered A tiles
  __shared__ int s_adj[ROWS * K_];       // 2304 B

  const int tid = (int)threadIdx.x;
  const int n0 = blockIdx.x * ROWS;

  for (int i = tid; i < ROWS * K_; i += 256)
    s_adj[i] = __builtin_nontemporal_load(adjc + (size_t)n0 * K_ + i);
  __syncthreads();

  const int w = tid >> 6;  // wave 0..3
  const int l = tid & 63;  // lane
  const int q = l >> 4;    // quad 0..3
  const int c = l & 15;

  // ---- DMA stage: wave w moves rows [w*16, w*16+16) of neighbor k into abuf[bf].
  // Each inst: 4 rows x 256 B; lane l -> row base+(l>>4), LDS chunk (l&15),
  // src chunk (l&15) ^ (row&7)  [XOR swizzle for bank-conflict-free reads].
  auto stage = [&](int k, int bf) {
#pragma unroll
    for (int j = 0; j < 4; ++j) {
      const int row = w * 16 + j * 4 + (l >> 4);  // per-lane row in tile
      const int src_chunk = (l & 15) ^ (row & 7);
      const size_t goff = (size_t)(unsigned)s_adj[row * K_ + k] * ROWB + (src_chunk << 4);
      const char* src = (const char*)xb + goff;
      short* dst = &abuf[bf][(w * 16 + j * 4) * 128];  // wave-uniform base
      __builtin_amdgcn_global_load_lds(
          (const __attribute__((address_space(1))) unsigned int*)src,
          (__attribute__((address_space(3))) unsigned int*)dst, 16, 0, 0);
    }
  };

  f32x4 acc[2][4];
#pragma unroll
  for (int p = 0; p < 2; ++p)
#pragma unroll
    for (int ct = 0; ct < 4; ++ct)
      acc[p][ct] = (f32x4){0.f, 0.f, 0.f, 0.f};

  stage(0, 0);

  for (int k = 0; k < K_; ++k) {
    __syncthreads();  // drains my DMA for stage k; syncs block
    if (k + 1 < K_) stage(k + 1, (k + 1) & 1);

    const short* bufk = abuf[k & 1];
    const int arow = (w * 16 + c) * 128;  // this lane's A row base (shorts)
#pragma unroll
    for (int fs = 0; fs < 2; ++fs) {
      const int ch0 = (fs * 4 + q) ^ (c & 7);        // plane 0 chunk (swizzled)
      const int ch1 = (8 + fs * 4 + q) ^ (c & 7);    // plane 1 chunk
      const short8 a0 = *(const short8*)&bufk[arow + (ch0 << 3)];
      const short8 a1 = *(const short8*)&bufk[arow + (ch1 << 3)];
      const short* wk = wt + (k << 12) + fs * 32 + q * 8 + (c << 6);  // + ct*1024
#pragma unroll
      for (int ct = 0; ct < 4; ++ct) {
        const short8 bf = *(const short8*)(wk + (ct << 10));
        acc[0][ct] = __builtin_amdgcn_mfma_f32_16x16x32_bf16(a0, bf, acc[0][ct], 0, 0, 0);
        acc[1][ct] = __builtin_amdgcn_mfma_f32_16x16x32_bf16(a1, bf, acc[1][ct], 0, 0, 0);
      }
    }
  }

  // Epilogue: C col = lane&15, row = quad*4 + reg; nontemporal stores.
  float bv[4];
#pragma unroll
  for (int ct = 0; ct < 4; ++ct) bv[ct] = bias[ct * 16 + c];

#pragma unroll
  for (int p = 0; p < 2; ++p) {
    const size_t outbase = ((size_t)p * N_ + (size_t)(n0 + w * 16)) * F_;
#pragma unroll
    for (int ct = 0; ct < 4; ++ct) {
#pragma unroll
      for (int rr = 0; rr < 4; ++rr) {
        const int row = q * 4 + rr;
        __builtin_nontemporal_store(acc[p][ct][rr] + bv[ct],
                                    &out[outbase + (size_t)row * F_ + ct * 16 + c]);
      }
    }
  }
}

extern "C" void kernel_launch(void* const* d_in, const int* in_sizes, int n_in,
                              void* d_out, int out_size, void* d_ws, size_t ws_size,
                              hipStream_t stream) {
  const float* x = (const float*)d_in[0];
  const int* adjc = (const int*)d_in[1];
  const float* W = (const float*)d_in[2];
  const float* bias = (const float*)d_in[3];
  float* out = (float*)d_out;

  unsigned short* xb = (unsigned short*)d_ws;  // 50,331,648 B
  unsigned short* wt = (unsigned short*)((char*)d_ws + (size_t)B_ * N_ * F_ * 2);

  cvt_x_kernel<<<6144, 256, 0, stream>>>(x, xb);
  cvt_w_kernel<<<144, 256, 0, stream>>>(W, wt);

  nhconv_main<<<N_ / ROWS, 256, 0, stream>>>((const short*)xb, adjc, (const short*)wt,
                                             bias, out);
}